// Round 7
// baseline (161.278 us; speedup 1.0000x reference)
//
#include <hip/hip_runtime.h>
#include <hip/hip_bf16.h>

typedef __attribute__((ext_vector_type(8))) __bf16 bf16x8;
typedef __attribute__((ext_vector_type(4))) __bf16 bf16x4;
typedef __attribute__((ext_vector_type(4))) float f32x4;

#define B_     2
#define N_     2048
#define DIM_   1024
#define INNER_ 512
#define H_     8
#define DH_    64
#define ROWS_  (B_ * N_)      // 4096
#define QKVN_  (3 * INNER_)   // 1536
#define SEGROWS_ 5120         // per-bh partial rows: 2048+1536+1024+512
#define QSCALE_ 11.5415603f   // 8 * log2(e): exp2-domain cosine scale
#define MAXL2_  11.5415603f   // fixed softmax max in exp2 domain

static __device__ __forceinline__ f32x4 mfma16(bf16x8 a, bf16x8 b, f32x4 c) {
    return __builtin_amdgcn_mfma_f32_16x16x32_bf16(a, b, c, 0, 0, 0);
}

static __device__ __forceinline__ void gld_lds16(const void* g, void* l) {
    __builtin_amdgcn_global_load_lds((const __attribute__((address_space(1))) void*)g,
                                     (__attribute__((address_space(3))) void*)l, 16, 0, 0);
}

// ---- prep: LayerNorm (blocks 0..4095) + both weight transposes (4096..) ---
__global__ __launch_bounds__(256) void prep_kernel(const float* __restrict__ x,
                                                   const float* __restrict__ lnw,
                                                   const float* __restrict__ lnb,
                                                   const float* __restrict__ wqkv,
                                                   const float* __restrict__ wout,
                                                   __bf16* __restrict__ xn,
                                                   __bf16* __restrict__ wqkvT,
                                                   __bf16* __restrict__ woutT) {
    int bid = blockIdx.x;
    int tid = threadIdx.x;
    if (bid < ROWS_) {
        // ---- LayerNorm row ----
        int row = bid;
        const float* xr = x + (size_t)row * DIM_;
        f32x4 xv = *reinterpret_cast<const f32x4*>(xr + tid * 4);
        float s  = xv.x + xv.y + xv.z + xv.w;
        float sq = xv.x * xv.x + xv.y * xv.y + xv.z * xv.z + xv.w * xv.w;
#pragma unroll
        for (int m = 1; m < 64; m <<= 1) {
            s  += __shfl_xor(s, m);
            sq += __shfl_xor(sq, m);
        }
        __shared__ float red[2][4];
        int wid = tid >> 6, lane = tid & 63;
        if (lane == 0) { red[0][wid] = s; red[1][wid] = sq; }
        __syncthreads();
        s  = red[0][0] + red[0][1] + red[0][2] + red[0][3];
        sq = red[1][0] + red[1][1] + red[1][2] + red[1][3];
        float mu   = s * (1.0f / DIM_);
        float var  = sq * (1.0f / DIM_) - mu * mu;
        float rstd = rsqrtf(var + 1e-5f);
        f32x4 wv = *reinterpret_cast<const f32x4*>(lnw + tid * 4);
        f32x4 bv = *reinterpret_cast<const f32x4*>(lnb + tid * 4);
        bf16x4 o;
#pragma unroll
        for (int j = 0; j < 4; ++j) o[j] = (__bf16)((xv[j] - mu) * rstd * wv[j] + bv[j]);
        *reinterpret_cast<bf16x4*>(xn + (size_t)row * DIM_ + tid * 4) = o;
        return;
    }
    // ---- weight transpose tiles ----
    __shared__ float t[64][65];
    bid -= ROWS_;
    const float* in; __bf16* out; int K, N, bx, by;
    if (bid < 384) { in = wqkv; out = wqkvT; K = DIM_;   N = QKVN_; bx = bid % 24; by = bid / 24; }
    else { bid -= 384; in = wout; out = woutT; K = INNER_; N = DIM_;  bx = bid % 16; by = bid / 16; }
    int n0 = bx * 64, k0 = by * 64;
    int w = tid >> 6, lane = tid & 63;
#pragma unroll
    for (int i = 0; i < 16; ++i) {
        int k = 16 * w + i;
        t[k][lane] = in[(size_t)(k0 + k) * N + n0 + lane];
    }
    __syncthreads();
#pragma unroll
    for (int i = 0; i < 16; ++i) {
        int n = 16 * w + i;
        out[(size_t)(n0 + n) * K + k0 + lane] = (__bf16)t[lane][n];
    }
}

// ------ fused QKV GEMM: 128x64 tile, BK=64; epilogue: l2norm Q/K rows ------
// (head-major) and DIRECT V-transpose writes into Vt[bh][64][2048].
__global__ __launch_bounds__(256) void gemm_qkv(const __bf16* __restrict__ A,
                                                const __bf16* __restrict__ Bt,
                                                __bf16* __restrict__ Qh,
                                                __bf16* __restrict__ Kh,
                                                __bf16* __restrict__ Vt) {
    const int K = DIM_;
    __shared__ __bf16 As[2][128 * 64];
    __shared__ __bf16 Bs[2][64 * 64];
    int id = blockIdx.x;
    int nid = (id & 7) * 96 + (id >> 3);     // XCD-chunked: 96 consecutive/XCD
    int bx = nid % 24, by = nid / 24;
    int tid = threadIdx.x;
    int w = tid >> 6, lane = tid & 63;
    int lr = lane & 15, lg = lane >> 4;
    int m0 = by * 128, n0 = bx * 64;
    int sr = tid >> 3;      // 0..31
    int sc8 = tid & 7;      // 16B chunk slot 0..7
    const __bf16* Ab = A  + (size_t)m0 * K;
    const __bf16* Bb = Bt + (size_t)n0 * K;
    f32x4 acc[2][4];
#pragma unroll
    for (int mi = 0; mi < 2; ++mi)
#pragma unroll
        for (int ci = 0; ci < 4; ++ci) acc[mi][ci] = f32x4{0.f, 0.f, 0.f, 0.f};

    auto stage = [&](int buf, int k0) {
#pragma unroll
        for (int i = 0; i < 4; ++i) {
            int r = sr + i * 32;
            int cs = sc8 ^ (r & 7);          // pre-swizzled source, linear dest
            gld_lds16(Ab + (size_t)r * K + k0 + 8 * cs, &As[buf][r * 64 + sc8 * 8]);
        }
#pragma unroll
        for (int i = 0; i < 2; ++i) {
            int r = sr + i * 32;
            int cs = sc8 ^ (r & 7);
            gld_lds16(Bb + (size_t)r * K + k0 + 8 * cs, &Bs[buf][r * 64 + sc8 * 8]);
        }
    };

    stage(0, 0);
    __syncthreads();
    int cur = 0;
    for (int k0 = 0; k0 < K; k0 += 64) {
        if (k0 + 64 < K) stage(cur ^ 1, k0 + 64);
        bf16x8 af[2][2], bfr[2][4];
#pragma unroll
        for (int kk = 0; kk < 2; ++kk) {
#pragma unroll
            for (int mi = 0; mi < 2; ++mi) {
                int r = w * 32 + 16 * mi + lr;
                af[kk][mi] = *reinterpret_cast<const bf16x8*>(
                    &As[cur][r * 64 + 8 * ((kk * 4 + lg) ^ (r & 7))]);
            }
#pragma unroll
            for (int ci = 0; ci < 4; ++ci) {
                int r = 16 * ci + lr;
                bfr[kk][ci] = *reinterpret_cast<const bf16x8*>(
                    &Bs[cur][r * 64 + 8 * ((kk * 4 + lg) ^ (r & 7))]);
            }
        }
#pragma unroll
        for (int kk = 0; kk < 2; ++kk)
#pragma unroll
            for (int mi = 0; mi < 2; ++mi)
#pragma unroll
                for (int ci = 0; ci < 4; ++ci)
                    acc[mi][ci] = mfma16(af[kk][mi], bfr[kk][ci], acc[mi][ci]);
        __syncthreads();
        cur ^= 1;
    }
    int u = bx;                        // 0..23: Q heads 0-7, K heads 8-15, V 16-23
    if (u >= 16) {
        // V block: write transposed directly. acc[..][ci][r] r=0..3 are 4
        // consecutive n for fixed d=16ci+lr -> packed 8B stores.
        int b = m0 >> 11;
        __bf16* Vb = Vt + ((size_t)(b * H_ + (u - 16))) * (DH_ * N_);
#pragma unroll
        for (int mi = 0; mi < 2; ++mi) {
            int nb = (m0 & 2047) + w * 32 + 16 * mi + 4 * lg;
#pragma unroll
            for (int ci = 0; ci < 4; ++ci) {
                int d = 16 * ci + lr;
                bf16x4 pk;
#pragma unroll
                for (int r = 0; r < 4; ++r) pk[r] = (__bf16)acc[mi][ci][r];
                *reinterpret_cast<bf16x4*>(Vb + (size_t)d * N_ + nb) = pk;
            }
        }
        return;
    }
    float smul = (u < 8) ? QSCALE_ : 1.0f;
    __bf16* base = (u < 8) ? (Qh + (size_t)u * N_ * DH_)
                           : (Kh + (size_t)(u - 8) * N_ * DH_);
#pragma unroll
    for (int mi = 0; mi < 2; ++mi)
#pragma unroll
        for (int r = 0; r < 4; ++r) {
            int grow = m0 + w * 32 + 16 * mi + 4 * lg + r;
            int b = grow >> 11, n = grow & 2047;
            float t = 0.f;
#pragma unroll
            for (int ci = 0; ci < 4; ++ci) t += acc[mi][ci][r] * acc[mi][ci][r];
#pragma unroll
            for (int m = 1; m < 16; m <<= 1) t += __shfl_xor(t, m);
            float sc2 = rsqrtf(t + 1e-12f) * smul;
            __bf16* dst = base + ((size_t)b * H_ * N_ + n) * DH_;
#pragma unroll
            for (int ci = 0; ci < 4; ++ci)
                dst[16 * ci + lr] = (__bf16)(acc[mi][ci][r] * sc2);
        }
}

// ------- causal flash attention, split-KV, FIXED-MAX softmax ---------------
__global__ __launch_bounds__(256) void attn_kernel(const __bf16* __restrict__ Qh,
                                                   const __bf16* __restrict__ Kh,
                                                   const __bf16* __restrict__ Vt,
                                                   float* __restrict__ Opart,
                                                   float* __restrict__ lpart) {
    __shared__ __bf16 Ks[2][64 * 64];
    __shared__ __bf16 Vs[2][64 * 64];
    __shared__ __bf16 pl[4][16 * 64];   // per-wave, XOR-swizzled
    int bh  = blockIdx.x & 15;
    int sid = blockIdx.x >> 4;           // 0..79, heavy-first order
    int s, qt;
    if (sid < 32)      { s = 0; qt = 31 - sid; }
    else if (sid < 56) { s = 1; qt = 31 - (sid - 32); }
    else if (sid < 72) { s = 2; qt = 31 - (sid - 56); }
    else               { s = 3; qt = 31 - (sid - 72); }
    int jt0 = 8 * s;
    int jt1 = min(8 * s + 7, qt);
    int tid = threadIdx.x;
    int w = tid >> 6, lane = tid & 63;
    int lr = lane & 15, lg = lane >> 4;
    int qrow = qt * 64 + 16 * w;
    const __bf16* Qp = Qh + (size_t)bh * N_ * DH_;
    const __bf16* Kp = Kh + (size_t)bh * N_ * DH_;
    const __bf16* Vp = Vt + (size_t)bh * DH_ * N_;
    bf16x8 qf0 = *reinterpret_cast<const bf16x8*>(Qp + (size_t)(qrow + lr) * DH_ + 8 * lg);
    bf16x8 qf1 = *reinterpret_cast<const bf16x8*>(Qp + (size_t)(qrow + lr) * DH_ + 32 + 8 * lg);
    bf16x8 ones;
#pragma unroll
    for (int j = 0; j < 8; ++j) ones[j] = (__bf16)1.0f;
    f32x4 oacc[4];
    f32x4 oacc4 = f32x4{0.f, 0.f, 0.f, 0.f};   // ones-column: row sums (l)
#pragma unroll
    for (int c = 0; c < 4; ++c) oacc[c] = f32x4{0.f, 0.f, 0.f, 0.f};
    int srow = tid >> 3, sc = tid & 7;

    auto stage = [&](int buf, int jb) {
#pragma unroll
        for (int q = 0; q < 2; ++q) {
            int row = q * 32 + srow;
            int cs = sc ^ (row & 7);
            gld_lds16(Kp + (size_t)(jb + row) * DH_ + 8 * cs,
                      &Ks[buf][(size_t)row * 64 + sc * 8]);
            gld_lds16(Vp + (size_t)row * N_ + jb + 8 * cs,
                      &Vs[buf][(size_t)row * 64 + sc * 8]);
        }
    };

    stage(0, jt0 * 64);
    __syncthreads();
    int cur = 0;
    for (int jt = jt0; jt <= jt1; ++jt) {
        int jb = jt * 64;
        if (jt < jt1) stage(cur ^ 1, jb + 64);
        const __bf16* ks = &Ks[cur][0];
        const __bf16* vs = &Vs[cur][0];
        f32x4 sm[4];
#pragma unroll
        for (int ch = 0; ch < 4; ++ch) {
            int row = 16 * ch + lr;
            bf16x8 k0 = *reinterpret_cast<const bf16x8*>(&ks[row * 64 + 8 * (lg ^ (row & 7))]);
            bf16x8 k1 = *reinterpret_cast<const bf16x8*>(&ks[row * 64 + 8 * ((4 + lg) ^ (row & 7))]);
            f32x4 t = f32x4{0.f, 0.f, 0.f, 0.f};
            t = mfma16(qf0, k0, t);
            t = mfma16(qf1, k1, t);
            sm[ch] = t;
        }
        f32x4 p[4];
        bool diag = (jt == qt);
#pragma unroll
        for (int ch = 0; ch < 4; ++ch)
#pragma unroll
            for (int r = 0; r < 4; ++r) {
                float pv = exp2f(sm[ch][r] - MAXL2_);
                if (diag) {
                    int qi = qrow + 4 * lg + r;
                    int j  = jb + 16 * ch + lr;
                    if (j > qi) pv = 0.f;
                }
                p[ch][r] = pv;
            }
        __bf16* plw = &pl[w][0];
#pragma unroll
        for (int ch = 0; ch < 4; ++ch)
#pragma unroll
            for (int r = 0; r < 4; ++r) {
                int row = 4 * lg + r, col = 16 * ch + lr;
                plw[row * 64 + (((col >> 3) ^ (row & 7)) << 3) + (col & 7)] = (__bf16)p[ch][r];
            }
        bf16x8 pf0 = *reinterpret_cast<const bf16x8*>(&plw[lr * 64 + ((lg ^ (lr & 7)) << 3)]);
        bf16x8 pf1 = *reinterpret_cast<const bf16x8*>(&plw[lr * 64 + (((4 + lg) ^ (lr & 7)) << 3)]);
#pragma unroll
        for (int dc = 0; dc < 4; ++dc) {
            int row = 16 * dc + lr;
            bf16x8 v0 = *reinterpret_cast<const bf16x8*>(&vs[row * 64 + 8 * (lg ^ (row & 7))]);
            bf16x8 v1 = *reinterpret_cast<const bf16x8*>(&vs[row * 64 + 8 * ((4 + lg) ^ (row & 7))]);
            oacc[dc] = mfma16(pf0, v0, oacc[dc]);
            oacc[dc] = mfma16(pf1, v1, oacc[dc]);
        }
        oacc4 = mfma16(pf0, ones, oacc4);
        oacc4 = mfma16(pf1, ones, oacc4);
        __syncthreads();
        cur ^= 1;
    }
    int soff = 2048 * s - 256 * s * (s - 1);   // {0,2048,3584,4608}
#pragma unroll
    for (int r = 0; r < 4; ++r) {
        int n = qrow + 4 * lg + r;
        size_t ridx = (size_t)bh * SEGROWS_ + soff + (n - 512 * s);
#pragma unroll
        for (int dc = 0; dc < 4; ++dc)
            Opart[ridx * 64 + 16 * dc + lr] = oacc[dc][r];
        if (lr == 0) lpart[ridx] = oacc4[r];
    }
}

// ---- out-proj GEMM with FUSED segment-combine A-staging -------------------
// 64x64 tile, BK=64 (one head per K-step). A = normalize(sum_s Opart) as bf16,
// reg-staged (loads issued before MFMA, written after). B via global_load_lds.
__global__ __launch_bounds__(256) void gemm_out(const float* __restrict__ Opart,
                                                const float* __restrict__ lpart,
                                                const __bf16* __restrict__ Bt,
                                                float* __restrict__ C) {
    const int K = INNER_, N = DIM_;
    __shared__ __bf16 As[2][64 * 64];
    __shared__ __bf16 Bs[2][64 * 64];
    int id = blockIdx.x;
    int nid = (id & 7) * 128 + (id >> 3);
    int bx = nid % 16, by = nid / 16;
    int tid = threadIdx.x;
    int w = tid >> 6, lane = tid & 63;
    int lr = lane & 15, lg = lane >> 4;
    int m0 = by * 64, n0 = bx * 64;
    int sr = tid >> 3, sc8 = tid & 7;
    const __bf16* Bb = Bt + (size_t)n0 * K;
    f32x4 acc[4];
#pragma unroll
    for (int ci = 0; ci < 4; ++ci) acc[ci] = f32x4{0.f, 0.f, 0.f, 0.f};

    // per-thread staged rows
    int rr0 = sr, rr1 = sr + 32;
    int d0 = 8 * sc8;

    auto stageB = [&](int buf, int k0) {
#pragma unroll
        for (int i = 0; i < 2; ++i) {
            int r = sr + i * 32;
            int cs = sc8 ^ (r & 7);
            gld_lds16(Bb + (size_t)r * K + k0 + 8 * cs, &Bs[buf][r * 64 + sc8 * 8]);
        }
    };

    auto loadA = [&](int h, f32x4& s0a, f32x4& s0b, f32x4& s1a, f32x4& s1b,
                     float& l0, float& l1) {
#pragma unroll
        for (int i = 0; i < 2; ++i) {
            int r = (i == 0) ? rr0 : rr1;
            int grow = m0 + r;
            int b = grow >> 11, n2 = grow & 2047;
            int smax = n2 >> 9;
            int bhh = b * H_ + h;
            f32x4 sa = f32x4{0.f, 0.f, 0.f, 0.f};
            f32x4 sb = f32x4{0.f, 0.f, 0.f, 0.f};
            float l = 0.f;
#pragma unroll
            for (int s = 0; s < 4; ++s)
                if (s <= smax) {
                    int soff = 2048 * s - 256 * s * (s - 1);
                    size_t ridx = (size_t)bhh * SEGROWS_ + soff + (n2 - 512 * s);
                    const float* p = Opart + ridx * 64 + d0;
                    sa += *reinterpret_cast<const f32x4*>(p);
                    sb += *reinterpret_cast<const f32x4*>(p + 4);
                    l  += lpart[ridx];
                }
            if (i == 0) { s0a = sa; s0b = sb; l0 = l; }
            else        { s1a = sa; s1b = sb; l1 = l; }
        }
    };

    auto writeA = [&](int buf, f32x4 s0a, f32x4 s0b, f32x4 s1a, f32x4 s1b,
                      float l0, float l1) {
#pragma unroll
        for (int i = 0; i < 2; ++i) {
            int r = (i == 0) ? rr0 : rr1;
            f32x4 va = (i == 0) ? s0a : s1a;
            f32x4 vb = (i == 0) ? s0b : s1b;
            float inv = 1.0f / ((i == 0) ? l0 : l1);
            bf16x8 o;
#pragma unroll
            for (int j = 0; j < 4; ++j) o[j]     = (__bf16)(va[j] * inv);
#pragma unroll
            for (int j = 0; j < 4; ++j) o[4 + j] = (__bf16)(vb[j] * inv);
            int slot = sc8 ^ (r & 7);
            *reinterpret_cast<bf16x8*>(&As[buf][r * 64 + slot * 8]) = o;
        }
    };

    // prologue: stage k0=0 (head 0)
    {
        f32x4 a0, b0, a1, b1; float l0, l1;
        loadA(0, a0, b0, a1, b1, l0, l1);
        stageB(0, 0);
        writeA(0, a0, b0, a1, b1, l0, l1);
    }
    __syncthreads();
    int cur = 0;
    for (int k0 = 0; k0 < K; k0 += 64) {
        bool more = (k0 + 64 < K);
        f32x4 a0, b0, a1, b1; float l0, l1;
        if (more) {
            loadA((k0 >> 6) + 1, a0, b0, a1, b1, l0, l1);   // issue early
            stageB(cur ^ 1, k0 + 64);
        }
        bf16x8 af[2], bfr[2][4];
#pragma unroll
        for (int kk = 0; kk < 2; ++kk) {
            int r = w * 16 + lr;
            af[kk] = *reinterpret_cast<const bf16x8*>(
                &As[cur][r * 64 + 8 * ((kk * 4 + lg) ^ (r & 7))]);
#pragma unroll
            for (int ci = 0; ci < 4; ++ci) {
                int rb = 16 * ci + lr;
                bfr[kk][ci] = *reinterpret_cast<const bf16x8*>(
                    &Bs[cur][rb * 64 + 8 * ((kk * 4 + lg) ^ (rb & 7))]);
            }
        }
#pragma unroll
        for (int kk = 0; kk < 2; ++kk)
#pragma unroll
            for (int ci = 0; ci < 4; ++ci)
                acc[ci] = mfma16(af[kk], bfr[kk][ci], acc[ci]);
        if (more) writeA(cur ^ 1, a0, b0, a1, b1, l0, l1);   // write late
        __syncthreads();
        cur ^= 1;
    }
#pragma unroll
    for (int ci = 0; ci < 4; ++ci)
#pragma unroll
        for (int r = 0; r < 4; ++r)
            C[(size_t)(m0 + w * 16 + 4 * lg + r) * N + n0 + 16 * ci + lr] = acc[ci][r];
}

extern "C" void kernel_launch(void* const* d_in, const int* in_sizes, int n_in,
                              void* d_out, int out_size, void* d_ws, size_t ws_size,
                              hipStream_t stream) {
    const float* x    = (const float*)d_in[0];
    const float* lnw  = (const float*)d_in[1];
    const float* lnb  = (const float*)d_in[2];
    const float* wqkv = (const float*)d_in[3];
    const float* wout = (const float*)d_in[4];
    float* out = (float*)d_out;

    char* ws = (char*)d_ws;
    size_t off = 0;
    auto alloc = [&](size_t bytes) -> char* {
        char* p = ws + off;
        off += (bytes + 255) & ~(size_t)255;
        return p;
    };
    __bf16* xn    = (__bf16*)alloc((size_t)ROWS_ * DIM_ * 2);
    __bf16* wqkvT = (__bf16*)alloc((size_t)QKVN_ * DIM_ * 2);
    __bf16* woutT = (__bf16*)alloc((size_t)DIM_ * INNER_ * 2);
    __bf16* Qhp   = (__bf16*)alloc((size_t)B_ * H_ * N_ * DH_ * 2);
    __bf16* Khp   = (__bf16*)alloc((size_t)B_ * H_ * N_ * DH_ * 2);
    __bf16* Vtp   = (__bf16*)alloc((size_t)B_ * H_ * DH_ * N_ * 2);
    float*  Opart = (float*)alloc((size_t)B_ * H_ * SEGROWS_ * DH_ * 4);
    float*  lbuf  = (float*)alloc((size_t)B_ * H_ * SEGROWS_ * 4);
    if (off > ws_size) return;

    prep_kernel<<<ROWS_ + 512, 256, 0, stream>>>(x, lnw, lnb, wqkv, wout, xn, wqkvT, woutT);
    gemm_qkv<<<768, 256, 0, stream>>>(xn, wqkvT, Qhp, Khp, Vtp);
    attn_kernel<<<1280, 256, 0, stream>>>(Qhp, Khp, Vtp, Opart, lbuf);
    gemm_out<<<1024, 256, 0, stream>>>(Opart, lbuf, woutT, out);
}

// Round 8
// 153.758 us; speedup vs baseline: 1.0489x; 1.0489x over previous
//
#include <hip/hip_runtime.h>
#include <hip/hip_bf16.h>

typedef __attribute__((ext_vector_type(8))) __bf16 bf16x8;
typedef __attribute__((ext_vector_type(4))) __bf16 bf16x4;
typedef __attribute__((ext_vector_type(4))) float f32x4;

#define B_     2
#define N_     2048
#define DIM_   1024
#define INNER_ 512
#define H_     8
#define DH_    64
#define ROWS_  (B_ * N_)      // 4096
#define QKVN_  (3 * INNER_)   // 1536
#define SEGROWS_ 5120         // per-bh partial rows: 2048+1536+1024+512
#define QSCALE_ 11.5415603f   // 8 * log2(e): exp2-domain cosine scale
#define MAXL2_  11.5415603f   // fixed softmax max in exp2 domain

static __device__ __forceinline__ f32x4 mfma16(bf16x8 a, bf16x8 b, f32x4 c) {
    return __builtin_amdgcn_mfma_f32_16x16x32_bf16(a, b, c, 0, 0, 0);
}

static __device__ __forceinline__ void gld_lds16(const void* g, void* l) {
    __builtin_amdgcn_global_load_lds((const __attribute__((address_space(1))) void*)g,
                                     (__attribute__((address_space(3))) void*)l, 16, 0, 0);
}

// ---- prep: LayerNorm (blocks 0..4095) + both weight transposes (4096..) ---
__global__ __launch_bounds__(256) void prep_kernel(const float* __restrict__ x,
                                                   const float* __restrict__ lnw,
                                                   const float* __restrict__ lnb,
                                                   const float* __restrict__ wqkv,
                                                   const float* __restrict__ wout,
                                                   __bf16* __restrict__ xn,
                                                   __bf16* __restrict__ wqkvT,
                                                   __bf16* __restrict__ woutT) {
    int bid = blockIdx.x;
    int tid = threadIdx.x;
    if (bid < ROWS_) {
        int row = bid;
        const float* xr = x + (size_t)row * DIM_;
        f32x4 xv = *reinterpret_cast<const f32x4*>(xr + tid * 4);
        float s  = xv.x + xv.y + xv.z + xv.w;
        float sq = xv.x * xv.x + xv.y * xv.y + xv.z * xv.z + xv.w * xv.w;
#pragma unroll
        for (int m = 1; m < 64; m <<= 1) {
            s  += __shfl_xor(s, m);
            sq += __shfl_xor(sq, m);
        }
        __shared__ float red[2][4];
        int wid = tid >> 6, lane = tid & 63;
        if (lane == 0) { red[0][wid] = s; red[1][wid] = sq; }
        __syncthreads();
        s  = red[0][0] + red[0][1] + red[0][2] + red[0][3];
        sq = red[1][0] + red[1][1] + red[1][2] + red[1][3];
        float mu   = s * (1.0f / DIM_);
        float var  = sq * (1.0f / DIM_) - mu * mu;
        float rstd = rsqrtf(var + 1e-5f);
        f32x4 wv = *reinterpret_cast<const f32x4*>(lnw + tid * 4);
        f32x4 bv = *reinterpret_cast<const f32x4*>(lnb + tid * 4);
        bf16x4 o;
#pragma unroll
        for (int j = 0; j < 4; ++j) o[j] = (__bf16)((xv[j] - mu) * rstd * wv[j] + bv[j]);
        *reinterpret_cast<bf16x4*>(xn + (size_t)row * DIM_ + tid * 4) = o;
        return;
    }
    __shared__ float t[64][65];
    bid -= ROWS_;
    const float* in; __bf16* out; int K, N, bx, by;
    if (bid < 384) { in = wqkv; out = wqkvT; K = DIM_;   N = QKVN_; bx = bid % 24; by = bid / 24; }
    else { bid -= 384; in = wout; out = woutT; K = INNER_; N = DIM_;  bx = bid % 16; by = bid / 16; }
    int n0 = bx * 64, k0 = by * 64;
    int w = tid >> 6, lane = tid & 63;
#pragma unroll
    for (int i = 0; i < 16; ++i) {
        int k = 16 * w + i;
        t[k][lane] = in[(size_t)(k0 + k) * N + n0 + lane];
    }
    __syncthreads();
#pragma unroll
    for (int i = 0; i < 16; ++i) {
        int n = 16 * w + i;
        out[(size_t)(n0 + n) * K + k0 + lane] = (__bf16)t[lane][n];
    }
}

// ------ fused QKV GEMM: 128x64 tile, BK=64, conflict-free 8-way swizzle ----
// grid 768 (XCD-chunked); l2norm epilogue, head-major Q/K; V row-major.
__global__ __launch_bounds__(256) void gemm_qkv(const __bf16* __restrict__ A,
                                                const __bf16* __restrict__ Bt,
                                                __bf16* __restrict__ Qh,
                                                __bf16* __restrict__ Kh,
                                                __bf16* __restrict__ Vrow) {
    const int K = DIM_;
    __shared__ __bf16 As[2][128 * 64];
    __shared__ __bf16 Bs[2][64 * 64];
    int id = blockIdx.x;
    int nid = (id & 7) * 96 + (id >> 3);
    int bx = nid % 24, by = nid / 24;
    int tid = threadIdx.x;
    int w = tid >> 6, lane = tid & 63;
    int lr = lane & 15, lg = lane >> 4;
    int m0 = by * 128, n0 = bx * 64;
    int sr = tid >> 3, sc8 = tid & 7;
    const __bf16* Ab = A  + (size_t)m0 * K;
    const __bf16* Bb = Bt + (size_t)n0 * K;
    f32x4 acc[2][4];
#pragma unroll
    for (int mi = 0; mi < 2; ++mi)
#pragma unroll
        for (int ci = 0; ci < 4; ++ci) acc[mi][ci] = f32x4{0.f, 0.f, 0.f, 0.f};

    auto stage = [&](int buf, int k0) {
#pragma unroll
        for (int i = 0; i < 4; ++i) {
            int r = sr + i * 32;
            int cs = sc8 ^ (r & 7);
            gld_lds16(Ab + (size_t)r * K + k0 + 8 * cs, &As[buf][r * 64 + sc8 * 8]);
        }
#pragma unroll
        for (int i = 0; i < 2; ++i) {
            int r = sr + i * 32;
            int cs = sc8 ^ (r & 7);
            gld_lds16(Bb + (size_t)r * K + k0 + 8 * cs, &Bs[buf][r * 64 + sc8 * 8]);
        }
    };

    stage(0, 0);
    __syncthreads();
    int cur = 0;
    for (int k0 = 0; k0 < K; k0 += 64) {
        if (k0 + 64 < K) stage(cur ^ 1, k0 + 64);
        bf16x8 af[2][2], bfr[2][4];
#pragma unroll
        for (int kk = 0; kk < 2; ++kk) {
#pragma unroll
            for (int mi = 0; mi < 2; ++mi) {
                int r = w * 32 + 16 * mi + lr;
                af[kk][mi] = *reinterpret_cast<const bf16x8*>(
                    &As[cur][r * 64 + 8 * ((kk * 4 + lg) ^ (r & 7))]);
            }
#pragma unroll
            for (int ci = 0; ci < 4; ++ci) {
                int r = 16 * ci + lr;
                bfr[kk][ci] = *reinterpret_cast<const bf16x8*>(
                    &Bs[cur][r * 64 + 8 * ((kk * 4 + lg) ^ (r & 7))]);
            }
        }
#pragma unroll
        for (int kk = 0; kk < 2; ++kk)
#pragma unroll
            for (int mi = 0; mi < 2; ++mi)
#pragma unroll
                for (int ci = 0; ci < 4; ++ci)
                    acc[mi][ci] = mfma16(af[kk][mi], bfr[kk][ci], acc[mi][ci]);
        __syncthreads();
        cur ^= 1;
    }
    int u = bx;                        // 0..23: Q heads 0-7, K heads 8-15, V 16-23
    bool isV = (u >= 16);
    float smul = (u < 8) ? QSCALE_ : 1.0f;
    __bf16* base;
    if (u < 8)       base = Qh   + (size_t)u * N_ * DH_;
    else if (u < 16) base = Kh   + (size_t)(u - 8) * N_ * DH_;
    else             base = Vrow + (size_t)(u - 16) * N_ * DH_;
#pragma unroll
    for (int mi = 0; mi < 2; ++mi)
#pragma unroll
        for (int r = 0; r < 4; ++r) {
            int grow = m0 + w * 32 + 16 * mi + 4 * lg + r;
            int b = grow >> 11, n = grow & 2047;
            float sc2 = 1.0f;
            if (!isV) {
                float t = 0.f;
#pragma unroll
                for (int ci = 0; ci < 4; ++ci) t += acc[mi][ci][r] * acc[mi][ci][r];
#pragma unroll
                for (int m = 1; m < 16; m <<= 1) t += __shfl_xor(t, m);
                sc2 = rsqrtf(t + 1e-12f) * smul;
            }
            __bf16* dst = base + ((size_t)b * H_ * N_ + n) * DH_;
#pragma unroll
            for (int ci = 0; ci < 4; ++ci)
                dst[16 * ci + lr] = (__bf16)(acc[mi][ci][r] * sc2);
        }
}

// ------------- V transpose per head: Vrow[bh][n][64] -> Vt[bh][64][n] ------
__global__ __launch_bounds__(256) void vtrans(const __bf16* __restrict__ Vrow,
                                              __bf16* __restrict__ Vt) {
    __shared__ __bf16 t[64][66];
    int bh = blockIdx.y, n0 = blockIdx.x * 64;
    int w = threadIdx.x >> 6, lane = threadIdx.x & 63;
#pragma unroll
    for (int i = 0; i < 16; ++i) {
        int nl = 16 * w + i;
        t[nl][lane] = Vrow[((size_t)bh * N_ + n0 + nl) * DH_ + lane];
    }
    __syncthreads();
#pragma unroll
    for (int i = 0; i < 16; ++i) {
        int d = 16 * w + i;
        Vt[(size_t)bh * DH_ * N_ + (size_t)d * N_ + n0 + lane] = t[lane][d];
    }
}

// ------- causal flash attention, split-KV, FIXED-MAX softmax ---------------
// LDS 32KB (dbuf K + single V + pl) -> 5 blocks/CU, all 1280 blocks resident.
// XCD-bh swizzle: each XCD serves 2 bh -> K/V L2-resident per XCD.
__global__ __launch_bounds__(256) void attn_kernel(const __bf16* __restrict__ Qh,
                                                   const __bf16* __restrict__ Kh,
                                                   const __bf16* __restrict__ Vt,
                                                   float* __restrict__ Opart,
                                                   float* __restrict__ lpart) {
    __shared__ __bf16 Ks[2][64 * 64];   // 16 KB
    __shared__ __bf16 Vs[64 * 64];      //  8 KB (single buffer)
    __shared__ __bf16 pl[4][16 * 64];   //  8 KB, per-wave XOR-swizzled
    int xcd = blockIdx.x & 7;
    int q   = blockIdx.x >> 3;           // 0..159
    int bh  = xcd * 2 + (q & 1);
    int sid = q >> 1;                    // 0..79, heavy-first order
    int s, qt;
    if (sid < 32)      { s = 0; qt = 31 - sid; }
    else if (sid < 56) { s = 1; qt = 31 - (sid - 32); }
    else if (sid < 72) { s = 2; qt = 31 - (sid - 56); }
    else               { s = 3; qt = 31 - (sid - 72); }
    int jt0 = 8 * s;
    int jt1 = min(8 * s + 7, qt);
    int tid = threadIdx.x;
    int w = tid >> 6, lane = tid & 63;
    int lr = lane & 15, lg = lane >> 4;
    int qrow = qt * 64 + 16 * w;
    const __bf16* Qp = Qh + (size_t)bh * N_ * DH_;
    const __bf16* Kp = Kh + (size_t)bh * N_ * DH_;
    const __bf16* Vp = Vt + (size_t)bh * DH_ * N_;
    bf16x8 qf0 = *reinterpret_cast<const bf16x8*>(Qp + (size_t)(qrow + lr) * DH_ + 8 * lg);
    bf16x8 qf1 = *reinterpret_cast<const bf16x8*>(Qp + (size_t)(qrow + lr) * DH_ + 32 + 8 * lg);
    bf16x8 ones;
#pragma unroll
    for (int j = 0; j < 8; ++j) ones[j] = (__bf16)1.0f;
    f32x4 oacc[4];
    f32x4 oacc4 = f32x4{0.f, 0.f, 0.f, 0.f};
#pragma unroll
    for (int c = 0; c < 4; ++c) oacc[c] = f32x4{0.f, 0.f, 0.f, 0.f};
    int srow = tid >> 3, sc = tid & 7;

    auto stageK = [&](int buf, int jb) {
#pragma unroll
        for (int qq = 0; qq < 2; ++qq) {
            int row = qq * 32 + srow;
            int cs = sc ^ (row & 7);
            gld_lds16(Kp + (size_t)(jb + row) * DH_ + 8 * cs,
                      &Ks[buf][(size_t)row * 64 + sc * 8]);
        }
    };
    auto stageV = [&](int jb) {
#pragma unroll
        for (int qq = 0; qq < 2; ++qq) {
            int row = qq * 32 + srow;   // row = d
            int cs = sc ^ (row & 7);
            gld_lds16(Vp + (size_t)row * N_ + jb + 8 * cs,
                      &Vs[(size_t)row * 64 + sc * 8]);
        }
    };

    stageK(0, jt0 * 64);
    stageV(jt0 * 64);
    __syncthreads();
    int cur = 0;
    for (int jt = jt0; jt <= jt1; ++jt) {
        int jb = jt * 64;
        if (jt < jt1) stageK(cur ^ 1, jb + 64);
        const __bf16* ks = &Ks[cur][0];
        f32x4 sm[4];
#pragma unroll
        for (int ch = 0; ch < 4; ++ch) {
            int row = 16 * ch + lr;
            bf16x8 k0 = *reinterpret_cast<const bf16x8*>(&ks[row * 64 + 8 * (lg ^ (row & 7))]);
            bf16x8 k1 = *reinterpret_cast<const bf16x8*>(&ks[row * 64 + 8 * ((4 + lg) ^ (row & 7))]);
            f32x4 t = f32x4{0.f, 0.f, 0.f, 0.f};
            t = mfma16(qf0, k0, t);
            t = mfma16(qf1, k1, t);
            sm[ch] = t;
        }
        f32x4 p[4];
        bool diag = (jt == qt);
#pragma unroll
        for (int ch = 0; ch < 4; ++ch)
#pragma unroll
            for (int r = 0; r < 4; ++r) {
                float pv = exp2f(sm[ch][r] - MAXL2_);
                if (diag) {
                    int qi = qrow + 4 * lg + r;
                    int j  = jb + 16 * ch + lr;
                    if (j > qi) pv = 0.f;
                }
                p[ch][r] = pv;
            }
        __bf16* plw = &pl[w][0];
#pragma unroll
        for (int ch = 0; ch < 4; ++ch)
#pragma unroll
            for (int r = 0; r < 4; ++r) {
                int row = 4 * lg + r, col = 16 * ch + lr;
                plw[row * 64 + (((col >> 3) ^ (row & 7)) << 3) + (col & 7)] = (__bf16)p[ch][r];
            }
        bf16x8 pf0 = *reinterpret_cast<const bf16x8*>(&plw[lr * 64 + ((lg ^ (lr & 7)) << 3)]);
        bf16x8 pf1 = *reinterpret_cast<const bf16x8*>(&plw[lr * 64 + (((4 + lg) ^ (lr & 7)) << 3)]);
        __syncthreads();   // B1: V(cur tile) staged by all waves (own vmcnt drained)
#pragma unroll
        for (int dc = 0; dc < 4; ++dc) {
            int row = 16 * dc + lr;
            bf16x8 v0 = *reinterpret_cast<const bf16x8*>(&Vs[row * 64 + 8 * (lg ^ (row & 7))]);
            bf16x8 v1 = *reinterpret_cast<const bf16x8*>(&Vs[row * 64 + 8 * ((4 + lg) ^ (row & 7))]);
            oacc[dc] = mfma16(pf0, v0, oacc[dc]);
            oacc[dc] = mfma16(pf1, v1, oacc[dc]);
        }
        oacc4 = mfma16(pf0, ones, oacc4);
        oacc4 = mfma16(pf1, ones, oacc4);
        __syncthreads();   // B2: PV done by all; safe to overwrite Vs / read next K
        if (jt < jt1) stageV(jb + 64);
        cur ^= 1;
    }
    int soff = 2048 * s - 256 * s * (s - 1);   // {0,2048,3584,4608}
#pragma unroll
    for (int r = 0; r < 4; ++r) {
        int n = qrow + 4 * lg + r;
        size_t ridx = (size_t)bh * SEGROWS_ + soff + (n - 512 * s);
#pragma unroll
        for (int dc = 0; dc < 4; ++dc)
            Opart[ridx * 64 + 16 * dc + lr] = oacc[dc][r];
        if (lr == 0) lpart[ridx] = oacc4[r];
    }
}

// ----------- combine partial segments -> normalized O (bf16) ---------------
__global__ __launch_bounds__(256) void combine_kernel(const float* __restrict__ Opart,
                                                      const float* __restrict__ lpart,
                                                      __bf16* __restrict__ Obp) {
    int gid = blockIdx.x * 4 + (threadIdx.x >> 6);   // q-row id 0..32767
    int lane = threadIdx.x & 63;
    int bh = gid >> 11, n = gid & 2047;
    int smax = n >> 9;
    float acc = 0.f, lsum = 0.f;
#pragma unroll
    for (int s = 0; s < 4; ++s)
        if (s <= smax) {
            int soff = 2048 * s - 256 * s * (s - 1);
            size_t ridx = (size_t)bh * SEGROWS_ + soff + (n - 512 * s);
            acc  += Opart[ridx * 64 + lane];
            lsum += lpart[ridx];
        }
    int b = bh >> 3, h = bh & 7;
    Obp[((size_t)(b * N_ + n)) * INNER_ + h * DH_ + lane] = (__bf16)(acc / lsum);
}

// ---- out-proj GEMM: 64x64 tile, BK=64, 1024 blocks (XCD-chunked) ----------
__global__ __launch_bounds__(256) void gemm_out(const __bf16* __restrict__ A,
                                                const __bf16* __restrict__ Bt,
                                                float* __restrict__ C) {
    const int K = INNER_, N = DIM_;
    __shared__ __bf16 As[2][64 * 64];
    __shared__ __bf16 Bs[2][64 * 64];
    int id = blockIdx.x;
    int nid = (id & 7) * 128 + (id >> 3);
    int bx = nid % 16, by = nid / 16;
    int tid = threadIdx.x;
    int w = tid >> 6, lane = tid & 63;
    int lr = lane & 15, lg = lane >> 4;
    int m0 = by * 64, n0 = bx * 64;
    int sr = tid >> 3, sc8 = tid & 7;
    const __bf16* Ab = A  + (size_t)m0 * K;
    const __bf16* Bb = Bt + (size_t)n0 * K;
    f32x4 acc[4];
#pragma unroll
    for (int ci = 0; ci < 4; ++ci) acc[ci] = f32x4{0.f, 0.f, 0.f, 0.f};

    auto stage = [&](int buf, int k0) {
#pragma unroll
        for (int i = 0; i < 2; ++i) {
            int r = sr + i * 32;
            int cs = sc8 ^ (r & 7);
            gld_lds16(Ab + (size_t)r * K + k0 + 8 * cs, &As[buf][r * 64 + sc8 * 8]);
            gld_lds16(Bb + (size_t)r * K + k0 + 8 * cs, &Bs[buf][r * 64 + sc8 * 8]);
        }
    };

    stage(0, 0);
    __syncthreads();
    int cur = 0;
    for (int k0 = 0; k0 < K; k0 += 64) {
        if (k0 + 64 < K) stage(cur ^ 1, k0 + 64);
        bf16x8 af[2], bfr[2][4];
#pragma unroll
        for (int kk = 0; kk < 2; ++kk) {
            int r = w * 16 + lr;
            af[kk] = *reinterpret_cast<const bf16x8*>(
                &As[cur][r * 64 + 8 * ((kk * 4 + lg) ^ (r & 7))]);
#pragma unroll
            for (int ci = 0; ci < 4; ++ci) {
                int rb = 16 * ci + lr;
                bfr[kk][ci] = *reinterpret_cast<const bf16x8*>(
                    &Bs[cur][rb * 64 + 8 * ((kk * 4 + lg) ^ (rb & 7))]);
            }
        }
#pragma unroll
        for (int kk = 0; kk < 2; ++kk)
#pragma unroll
            for (int ci = 0; ci < 4; ++ci)
                acc[ci] = mfma16(af[kk], bfr[kk][ci], acc[ci]);
        __syncthreads();
        cur ^= 1;
    }
#pragma unroll
    for (int ci = 0; ci < 4; ++ci)
#pragma unroll
        for (int r = 0; r < 4; ++r)
            C[(size_t)(m0 + w * 16 + 4 * lg + r) * N + n0 + 16 * ci + lr] = acc[ci][r];
}

extern "C" void kernel_launch(void* const* d_in, const int* in_sizes, int n_in,
                              void* d_out, int out_size, void* d_ws, size_t ws_size,
                              hipStream_t stream) {
    const float* x    = (const float*)d_in[0];
    const float* lnw  = (const float*)d_in[1];
    const float* lnb  = (const float*)d_in[2];
    const float* wqkv = (const float*)d_in[3];
    const float* wout = (const float*)d_in[4];
    float* out = (float*)d_out;

    char* ws = (char*)d_ws;
    size_t off = 0;
    auto alloc = [&](size_t bytes) -> char* {
        char* p = ws + off;
        off += (bytes + 255) & ~(size_t)255;
        return p;
    };
    __bf16* xn    = (__bf16*)alloc((size_t)ROWS_ * DIM_ * 2);
    __bf16* wqkvT = (__bf16*)alloc((size_t)QKVN_ * DIM_ * 2);
    __bf16* woutT = (__bf16*)alloc((size_t)DIM_ * INNER_ * 2);
    __bf16* Qhp   = (__bf16*)alloc((size_t)B_ * H_ * N_ * DH_ * 2);
    __bf16* Khp   = (__bf16*)alloc((size_t)B_ * H_ * N_ * DH_ * 2);
    __bf16* Vrow  = (__bf16*)alloc((size_t)B_ * H_ * N_ * DH_ * 2);
    __bf16* Vtp   = (__bf16*)alloc((size_t)B_ * H_ * DH_ * N_ * 2);
    __bf16* Obp   = (__bf16*)alloc((size_t)ROWS_ * INNER_ * 2);
    float*  Opart = (float*)alloc((size_t)B_ * H_ * SEGROWS_ * DH_ * 4);
    float*  lbuf  = (float*)alloc((size_t)B_ * H_ * SEGROWS_ * 4);
    if (off > ws_size) return;

    prep_kernel<<<ROWS_ + 512, 256, 0, stream>>>(x, lnw, lnb, wqkv, wout, xn, wqkvT, woutT);
    gemm_qkv<<<768, 256, 0, stream>>>(xn, wqkvT, Qhp, Khp, Vrow);
    vtrans<<<dim3(N_ / 64, B_ * H_), 256, 0, stream>>>(Vrow, Vtp);
    attn_kernel<<<1280, 256, 0, stream>>>(Qhp, Khp, Vtp, Opart, lbuf);
    combine_kernel<<<(ROWS_ * H_) / 4, 256, 0, stream>>>(Opart, lbuf, Obp);
    gemm_out<<<1024, 256, 0, stream>>>(Obp, woutT, out);
}